// Round 5
// baseline (231.517 us; speedup 1.0000x reference)
//
#include <hip/hip_runtime.h>

// FRFT with diagonal transform matrices (Evec = I in the reference):
//   out[n,c,h,w] = Re( D[(h+128)%256] * D[(w+128)%256] ) * x[n,c,h,w]
// where D[i] = 16 * exp(-i * (pi/2) * a * l_i),  l_i = i (i<255), l_255 = 256.
//
// HARNESS FACTS (rocprof rounds 2-4):
//  - Live output is REAL-only, 134 MB f32 (WRITE_SIZE == 131072 KB);
//    interleaved path is a dead fallback.
//  - ~Half the input reads hit Infinity Cache (FETCH ~65 MB of 134 MB).
//  - NT stores REGRESS (~82 µs vs <79 µs plain): plain stores through L2
//    sustain 6.7 TB/s (fill kernels prove it). Keep plain stores.
//  - dur_us = 2 harness fills (~160 µs, fixed) + kernel. Copy roofline for
//    the kernel: 268 MB @ 6.3 TB/s = 43 µs; round-4 kernel ~70 µs.
//
// Round-6 changes:
//  1. Two-kernel launch: a 1-block table kernel computes the 256-entry
//     16*(cos,sin) diagonal (double sincos) into d_ws ONCE; the main kernel
//     loads 2 KB from global into LDS. Previously all 8192 blocks redundantly
//     ran a ~several-hundred-cycle double sincos prologue (~8-10 µs/CU of
//     serial f64 VALU) before streaming a single byte.
//  2. Branch-free hot path: nvec4 % (BLOCK*KIT) == 0 for this shape, so the
//     full-tile path has no per-k guards/cndmasks. Guarded generic path kept
//     only for odd shapes / the dead interleaved mode.
//  3. KIT=8 f32x4 vectors per thread, all loads issued back-to-back into
//     named registers (128 B/lane in flight), then compute + plain
//     global_store_dwordx4 drain. Structurally the m13 copy pattern.
//  4. Fallback: if d_ws is unusable, main kernel builds the table in-kernel
//     (round-4 behavior) — correctness never depends on workspace.

typedef float f32x2 __attribute__((ext_vector_type(2)));
typedef float f32x4 __attribute__((ext_vector_type(4)));

constexpr int HW    = 256;  // H == W == 256
constexpr int BLOCK = 256;
constexpr int KIT   = 8;    // f32x4 vectors per thread (32 elements)

__device__ __forceinline__ f32x2 diag_entry(const float* order, int t) {
    const int idx = t ^ 128;                       // (t + 128) % 256
    const double l = (idx == 255) ? 256.0 : (double)idx;
    const double theta = 1.5707963267948966 * (double)order[0] * l;
    double s, c;
    sincos(theta, &s, &c);
    return (f32x2){(float)(16.0 * c), (float)(16.0 * s)};
}

__global__ __launch_bounds__(BLOCK) void frft_table_kernel(
    const float* __restrict__ order, float* __restrict__ tbl_g)
{
    const int t = threadIdx.x;
    ((f32x2*)tbl_g)[t] = diag_entry(order, t);
}

__global__ __launch_bounds__(BLOCK) void frft_diag_kernel(
    const float* __restrict__ x,
    const float* __restrict__ order,
    const float* __restrict__ tbl_g,   // precomputed table in d_ws (or null)
    float* __restrict__ out,
    int interleaved,
    int nvec4)   // number of f32x4 input vectors = total/4
{
    __shared__ alignas(16) f32x2 tbl[HW];
    const int t = threadIdx.x;
    if (tbl_g) {
        tbl[t] = ((const f32x2*)tbl_g)[t];         // 2 KB, L2-resident
    } else {
        tbl[t] = diag_entry(order, t);             // fallback (round-4 path)
    }
    __syncthreads();

    // Element index e = 4p, so w = e & 255 = 4*(t & 63): lane-invariant.
    const int wbase = (t & 63) << 2;
    const f32x4 twA = *reinterpret_cast<const f32x4*>(&tbl[wbase]);      // c0,s0,c1,s1
    const f32x4 twB = *reinterpret_cast<const f32x4*>(&tbl[wbase + 2]);  // c2,s2,c3,s3

    const int base = blockIdx.x * (BLOCK * KIT) + t;   // f32x4 index, k-stride BLOCK

    if (!interleaved && base + (KIT - 1) * BLOCK < nvec4) {
        // ---- hot path: full tile, real-only output, branch-free ----
        f32x4 xv[KIT];
#pragma unroll
        for (int k = 0; k < KIT; ++k)                  // 8 back-to-back dwordx4
            xv[k] = ((const f32x4*)x)[base + k * BLOCK];

#pragma unroll
        for (int k = 0; k < KIT; ++k) {
            const int p = base + k * BLOCK;
            const f32x2 th = tbl[(p >> 6) & (HW - 1)]; // wave-uniform ds_read_b64
            // Re[(ch - i*sh)(cw - i*sw)] = ch*cw - sh*sw
            const float pr0 = th.x * twA.x - th.y * twA.y;
            const float pr1 = th.x * twA.z - th.y * twA.w;
            const float pr2 = th.x * twB.x - th.y * twB.y;
            const float pr3 = th.x * twB.z - th.y * twB.w;
            f32x4 o = { xv[k].x * pr0, xv[k].y * pr1, xv[k].z * pr2, xv[k].w * pr3 };
            ((f32x4*)out)[p] = o;                      // plain global_store_dwordx4
        }
        return;
    }

    // ---- generic guarded path (tails / dead interleaved mode) ----
#pragma unroll
    for (int k = 0; k < KIT; ++k) {
        const int p = base + k * BLOCK;
        if (p >= nvec4) continue;
        const f32x4 xv = ((const f32x4*)x)[p];
        const f32x2 th = tbl[(p >> 6) & (HW - 1)];
        const float pr0 = th.x * twA.x - th.y * twA.y;
        const float pr1 = th.x * twA.z - th.y * twA.w;
        const float pr2 = th.x * twB.x - th.y * twB.y;
        const float pr3 = th.x * twB.z - th.y * twB.w;
        if (interleaved) {
            const float pi0 = th.x * twA.y + th.y * twA.x;
            const float pi1 = th.x * twA.w + th.y * twA.z;
            const float pi2 = th.x * twB.y + th.y * twB.x;
            const float pi3 = th.x * twB.w + th.y * twB.z;
            f32x4 oA = { xv.x * pr0, -xv.x * pi0, xv.y * pr1, -xv.y * pi1 };
            f32x4 oB = { xv.z * pr2, -xv.z * pi2, xv.w * pr3, -xv.w * pi3 };
            ((f32x4*)out)[2 * p]     = oA;
            ((f32x4*)out)[2 * p + 1] = oB;
        } else {
            f32x4 o = { xv.x * pr0, xv.y * pr1, xv.z * pr2, xv.w * pr3 };
            ((f32x4*)out)[p] = o;
        }
    }
}

extern "C" void kernel_launch(void* const* d_in, const int* in_sizes, int n_in,
                              void* d_out, int out_size, void* d_ws, size_t ws_size,
                              hipStream_t stream) {
    const float* x     = (const float*)d_in[0];
    const float* order = (const float*)d_in[1];
    float* out = (float*)d_out;

    const int total = in_sizes[0];          // element count
    const int nvec4 = total / 4;            // f32x4 vectors
    const int interleaved = (out_size >= 2 * total) ? 1 : 0;

    float* tbl_g = nullptr;
    if (d_ws && ws_size >= HW * sizeof(f32x2)) {
        tbl_g = (float*)d_ws;
        frft_table_kernel<<<1, BLOCK, 0, stream>>>(order, tbl_g);
    }

    const int per_block = BLOCK * KIT;      // 2048 f32x4 per block
    const int grid = (nvec4 + per_block - 1) / per_block;
    frft_diag_kernel<<<grid, BLOCK, 0, stream>>>(x, order, tbl_g, out,
                                                 interleaved, nvec4);
}

// Round 6
// 222.390 us; speedup vs baseline: 1.0410x; 1.0410x over previous
//
#include <hip/hip_runtime.h>

// FRFT with diagonal transform matrices (Evec = I in the reference):
//   out[n,c,h,w] = Re( D[(h+128)%256] * D[(w+128)%256] ) * x[n,c,h,w]
// where D[i] = 16 * exp(-i * (pi/2) * a * l_i),  l_i = i (i<255), l_255 = 256.
//
// HARNESS FACTS (rocprof rounds 0-5):
//  - Live output is REAL-only, 134 MB f32 (WRITE_SIZE == 131072 KB);
//    interleaved complex path is a dead fallback. Sizes are in ELEMENTS.
//  - dur_us ≈ 2 x 80.2 µs poison fills (512 MB each, 6.7 TB/s, fixed) + kernel.
//  - Kernel landed 66-73 µs across 5 structurally different versions
//    (8 B vs 16 B lanes, NT vs plain, KIT=1..8, table-kernel vs in-block):
//    structure-insensitive, ~2.9 TB/s HBM-side. Device-aggregate per
//    iteration = 1.22 GB / 230 µs = 5.3 TB/s ~= 80% of demonstrated BW ->
//    the kernel window shares HBM with the fills' dirty-line drain.
//  - NT stores regress (+6 µs). Plain stores through L2 win.
//  - Best so far: round-0's max-parallelism shape (KIT=1, 65536 blocks).
//
// Round-6: r0's shape with every verified micro-win folded in:
//  - KIT=1, grid = nvec4/256 = 32768 blocks (max resident parallelism --
//    r0/r4/r5 trend: 66 -> 70 -> 71 µs as blocks shrank 8x).
//  - f32x4 load AND store (16 B/lane dense; r0 was 8 B/lane).
//  - Global load issued BEFORE the sincos prologue: the ~900-cycle HBM
//    latency hides under the f64 table build instead of stalling after
//    the barrier.
//  - No separate table kernel (r5's extra launch serialized ~2 µs).
//  - Lane-invariant w-factors hoisted from LDS once; wave-uniform tbl[h]
//    broadcast (ds_read_b64, conflict-free).

typedef float f32x2 __attribute__((ext_vector_type(2)));
typedef float f32x4 __attribute__((ext_vector_type(4)));

constexpr int HW    = 256;  // H == W == 256
constexpr int BLOCK = 256;

__global__ __launch_bounds__(BLOCK) void frft_diag_kernel(
    const float* __restrict__ x,
    const float* __restrict__ order,
    float* __restrict__ out,
    int interleaved,
    int nvec4)   // number of f32x4 input vectors = total/4
{
    __shared__ alignas(16) f32x2 tbl[HW];

    const int t = threadIdx.x;
    const int p = blockIdx.x * BLOCK + t;              // f32x4 index
    const bool live = (p < nvec4);

    // Issue the streaming load FIRST: independent of the table, so its
    // latency hides under the f64 sincos prologue below.
    f32x4 xv = {0, 0, 0, 0};
    if (live) xv = ((const f32x4*)x)[p];               // global_load_dwordx4

    // Build the shifted diagonal table once per block. Double precision:
    // phase reaches ~2400 rad; double sincos keeps argument-reduction
    // error negligible vs the 2% threshold. (r0 proved this prologue is
    // fully hidden under the memory stream.)
    {
        const int idx = t ^ 128;                       // (t + 128) % 256
        const double l = (idx == 255) ? 256.0 : (double)idx;
        const double theta = 1.5707963267948966 * (double)order[0] * l;
        double s, c;
        sincos(theta, &s, &c);
        tbl[t] = (f32x2){(float)(16.0 * c), (float)(16.0 * s)};
    }
    __syncthreads();

    if (!live) return;

    // Element index e = 4p, so w = e & 255 = 4*(t & 63): lane-invariant.
    const int wbase = (t & 63) << 2;
    const f32x4 twA = *reinterpret_cast<const f32x4*>(&tbl[wbase]);      // c0,s0,c1,s1
    const f32x4 twB = *reinterpret_cast<const f32x4*>(&tbl[wbase + 2]);  // c2,s2,c3,s3
    const f32x2 th  = tbl[(p >> 6) & (HW - 1)];        // wave-uniform ds_read_b64

    // Re[(ch - i*sh)(cw - i*sw)] = ch*cw - sh*sw
    const float pr0 = th.x * twA.x - th.y * twA.y;
    const float pr1 = th.x * twA.z - th.y * twA.w;
    const float pr2 = th.x * twB.x - th.y * twB.y;
    const float pr3 = th.x * twB.z - th.y * twB.w;

    if (interleaved) {
        // Dead in this harness (output is real-only); kept for safety.
        const float pi0 = th.x * twA.y + th.y * twA.x;
        const float pi1 = th.x * twA.w + th.y * twA.z;
        const float pi2 = th.x * twB.y + th.y * twB.x;
        const float pi3 = th.x * twB.w + th.y * twB.z;
        f32x4 oA = { xv.x * pr0, -xv.x * pi0, xv.y * pr1, -xv.y * pi1 };
        f32x4 oB = { xv.z * pr2, -xv.z * pi2, xv.w * pr3, -xv.w * pi3 };
        ((f32x4*)out)[2 * p]     = oA;
        ((f32x4*)out)[2 * p + 1] = oB;
    } else {
        f32x4 o = { xv.x * pr0, xv.y * pr1, xv.z * pr2, xv.w * pr3 };
        ((f32x4*)out)[p] = o;                          // plain global_store_dwordx4
    }
}

extern "C" void kernel_launch(void* const* d_in, const int* in_sizes, int n_in,
                              void* d_out, int out_size, void* d_ws, size_t ws_size,
                              hipStream_t stream) {
    const float* x     = (const float*)d_in[0];
    const float* order = (const float*)d_in[1];
    float* out = (float*)d_out;

    const int total = in_sizes[0];          // element count
    const int nvec4 = total / 4;            // f32x4 vectors
    const int interleaved = (out_size >= 2 * total) ? 1 : 0;

    const int grid = (nvec4 + BLOCK - 1) / BLOCK;      // 32768 blocks
    frft_diag_kernel<<<grid, BLOCK, 0, stream>>>(x, order, out, interleaved, nvec4);
}